// Round 9
// baseline (840.947 us; speedup 1.0000x reference)
//
#include <hip/hip_runtime.h>
#include <stdint.h>
#include <stddef.h>

// Problem constants (fixed by the reference)
#define M_ROWS 32768      // B*N = 16*2048
#define N_CODES 8192
#define K_DIM 512
#define BM 128
#define BN 128
#define BK 64
#define KITERS (K_DIM / BK)     // 8
#define CAND_CAP (3u*1024u*1024u)
#define LCAP 512u               // per-block LDS candidate slab
#define TAU2 2.0f               // 2*tau admission margin for bf16 approx distances (>10 sigma)

// Output layout (floats): z_q [0,16777216), codes [16777216,16809984), loss, perp
#define OFF_CODES 16777216
#define OFF_LOSS  (16777216 + 32768)
#define OFF_PERP  (16777216 + 32768 + 1)

using short8  = __attribute__((ext_vector_type(8))) short;
using ushort8 = __attribute__((ext_vector_type(8))) unsigned short;
using f32x4   = __attribute__((ext_vector_type(4))) float;

typedef unsigned short u16;
typedef unsigned int   u32;
typedef unsigned long long u64;

// ---- orderable-uint encoding of float (monotone: uint min == float min) ----
__device__ __forceinline__ u32 ford(float f) {
    u32 u = __float_as_uint(f);
    return (u & 0x80000000u) ? ~u : (u | 0x80000000u);
}
__device__ __forceinline__ float fordinv(u32 u) {
    u32 v = (u & 0x80000000u) ? (u & 0x7FFFFFFFu) : ~u;
    return __uint_as_float(v);
}
// fp32 -> bf16 (RNE)
__device__ __forceinline__ u16 f2bf(float f) {
    u32 u = __float_as_uint(f);
    u = u + 0x7FFFu + ((u >> 16) & 1u);
    return (u16)(u >> 16);
}

// async global->LDS, 16B per lane; LDS dest = wave-uniform base + lane*16
__device__ __forceinline__ void ldg_to_lds16(const u16* g, u16* l) {
    __builtin_amdgcn_global_load_lds((__attribute__((address_space(1))) void*)(g),
                                     (__attribute__((address_space(3))) void*)(l),
                                     16, 0, 0);
}

// ------------- fused convert (z AND emb in one launch) + scratch init -------------
// blocks [0,8192): z rows (4/block) + all scratch init; blocks [8192,10240): emb rows.
// (R8-verified piece; cooperative tail was the R8 regression, not this.)
__global__ void k_convert(const float* __restrict__ z, const float* __restrict__ emb,
                          u16* __restrict__ zb, u16* __restrict__ eb,
                          float* __restrict__ zn2, float* __restrict__ en2,
                          u32* rowMin, u64* rowBest, u32* counts, u32* candCnt,
                          float* fsum, u32* ticket) {
    int b = blockIdx.x;
    const float* src; u16* dst; float* nrm2; int row;
    if (b < 8192) {
        int g = b * blockDim.x + threadIdx.x;
        if (g < M_ROWS) { rowMin[g] = 0xFFFFFFFFu; rowBest[g] = ~0ull; }
        if (g < N_CODES) counts[g] = 0u;
        if (g == 0) { *candCnt = 0u; *fsum = 0.f; *ticket = 0u; }
        src = z; dst = zb; nrm2 = zn2; row = b * 4 + (threadIdx.x >> 6);
    } else {
        src = emb; dst = eb; nrm2 = en2; row = (b - 8192) * 4 + (threadIdx.x >> 6);
    }
    int lane = threadIdx.x & 63;
    const float* p = src + (size_t)row * K_DIM + lane * 8;
    float4 a = *(const float4*)p;
    float4 bb = *(const float4*)(p + 4);
    ushort8 v;
    v[0]=f2bf(a.x); v[1]=f2bf(a.y); v[2]=f2bf(a.z); v[3]=f2bf(a.w);
    v[4]=f2bf(bb.x); v[5]=f2bf(bb.y); v[6]=f2bf(bb.z); v[7]=f2bf(bb.w);
    *(ushort8*)(dst + (size_t)row * K_DIM + lane * 8) = v;
    float ss = a.x*a.x + a.y*a.y + a.z*a.z + a.w*a.w
             + bb.x*bb.x + bb.y*bb.y + bb.z*bb.z + bb.w*bb.w;
    #pragma unroll
    for (int s = 32; s; s >>= 1) ss += __shfl_xor(ss, s);
    if (lane == 0) nrm2[row] = ss;
}

// ---------------- main bf16 GEMM + fused min/candidate epilogue ----------------
// PROVEN baseline structure (R6/R7: 420-423us, MfmaUtil 29%, Occ 41% = 4 blocks/CU).
// Coarse 2-barriers-per-K-step + 16 waves/CU cross-block overlap beats all
// fine-grained phase pipelines at this short K (R2-R5 evidence). DO NOT
// re-pipeline without first beating 420us in isolation. BYTE-IDENTICAL to R7.
__global__ __launch_bounds__(256, 4)
void k_gemm(const u16* __restrict__ zb, const u16* __restrict__ eb,
            const float* __restrict__ en2, u32* __restrict__ rowMin,
            u32* __restrict__ candCnt, u64* __restrict__ cand) {
    __shared__ __align__(16) u16 As[BM * BK];
    __shared__ __align__(16) u16 Bs[BN * BK];
    __shared__ float en2s[BN];
    __shared__ u32 threshL[BM];
    __shared__ u64 candBuf[LCAP];
    __shared__ u32 ldsCnt, ldsBase;

    const int tid  = threadIdx.x;
    const int lane = tid & 63;
    const int wave = tid >> 6;
    const int rowTile = blockIdx.x * BM;
    const int nTile   = blockIdx.y * BN;
    const int wm = (wave >> 1) * 64;   // wave's row quadrant
    const int wn = (wave & 1) * 64;    // wave's col quadrant

    if (tid < BN) { en2s[tid] = en2[nTile + tid]; threshL[tid] = 0xFFFFFFFFu; }
    if (tid == 0) ldsCnt = 0u;

    const int srow = (lane >> 3);
    const int sg   = (lane & 7) ^ ((lane >> 3) & 7);
    const u16* gA[4]; const u16* gB[4]; u16* lA[4]; u16* lB[4];
    #pragma unroll
    for (int t = 0; t < 4; t++) {
        int i = wave * 4 + t;
        gA[t] = zb + (size_t)(rowTile + i * 8 + srow) * K_DIM + sg * 8;
        gB[t] = eb + (size_t)(nTile   + i * 8 + srow) * K_DIM + sg * 8;
        lA[t] = As + i * 512;   // 64 blocks * 8 u16 per wave-issue
        lB[t] = Bs + i * 512;
    }

    int aoff[4], boff[4];
    const int q = lane >> 4;
    #pragma unroll
    for (int t = 0; t < 4; t++) {
        int R  = wm + t * 16 + (lane & 15);
        aoff[t] = (R * 8 + (q ^ (R & 7))) * 16;
        int Rn = wn + t * 16 + (lane & 15);
        boff[t] = (Rn * 8 + (q ^ (Rn & 7))) * 16;
    }

    f32x4 acc[4][4] = {};

    for (int kk = 0; kk < KITERS; kk++) {
        const int ko = kk * BK;
        #pragma unroll
        for (int t = 0; t < 4; t++) {
            ldg_to_lds16(gA[t] + ko, lA[t]);
            ldg_to_lds16(gB[t] + ko, lB[t]);
        }
        __syncthreads();
        short8 af[4], bf_[4];
        #pragma unroll
        for (int t = 0; t < 4; t++) {
            af[t]  = *(const short8*)((const char*)As + aoff[t]);
            bf_[t] = *(const short8*)((const char*)Bs + boff[t]);
        }
        #pragma unroll
        for (int i = 0; i < 4; i++)
            #pragma unroll
            for (int j = 0; j < 4; j++)
                acc[i][j] = __builtin_amdgcn_mfma_f32_16x16x32_bf16(af[i], bf_[j], acc[i][j], 0, 0, 0);
        #pragma unroll
        for (int t = 0; t < 4; t++) {
            af[t]  = *(const short8*)((const char*)As + (aoff[t] ^ 64));
            bf_[t] = *(const short8*)((const char*)Bs + (boff[t] ^ 64));
        }
        #pragma unroll
        for (int i = 0; i < 4; i++)
            #pragma unroll
            for (int j = 0; j < 4; j++)
                acc[i][j] = __builtin_amdgcn_mfma_f32_16x16x32_bf16(af[i], bf_[j], acc[i][j], 0, 0, 0);
        __syncthreads();
    }

    float e2v[4];
    #pragma unroll
    for (int j = 0; j < 4; j++) e2v[j] = en2s[wn + j * 16 + (lane & 15)];
    #pragma unroll
    for (int i = 0; i < 4; i++)
        #pragma unroll
        for (int j = 0; j < 4; j++)
            #pragma unroll
            for (int r = 0; r < 4; r++)
                acc[i][j][r] = e2v[j] - 2.0f * acc[i][j][r];

    float rm[4][4];
    #pragma unroll
    for (int i = 0; i < 4; i++)
        #pragma unroll
        for (int r = 0; r < 4; r++)
            rm[i][r] = fminf(fminf(acc[i][0][r], acc[i][1][r]),
                             fminf(acc[i][2][r], acc[i][3][r]));
    #pragma unroll
    for (int d = 1; d < 16; d <<= 1)
        #pragma unroll
        for (int i = 0; i < 4; i++)
            #pragma unroll
            for (int r = 0; r < 4; r++)
                rm[i][r] = fminf(rm[i][r], __shfl_xor(rm[i][r], d));

    if ((lane & 15) == 0) {
        #pragma unroll
        for (int i = 0; i < 4; i++)
            #pragma unroll
            for (int r = 0; r < 4; r++) {
                int lrow = wm + i * 16 + (lane >> 4) * 4 + r;
                u32 o = ford(rm[i][r]);
                atomicMin(&threshL[lrow], o);
                u32 old = atomicMin(&rowMin[rowTile + lrow], o);  // also tightens via earlier tiles
                atomicMin(&threshL[lrow], old);
            }
    }
    __syncthreads();

    #pragma unroll
    for (int i = 0; i < 4; i++) {
        #pragma unroll
        for (int r = 0; r < 4; r++) {
            int lrow = wm + i * 16 + (lane >> 4) * 4 + r;
            float th = fordinv(threshL[lrow]) + TAU2;
            #pragma unroll
            for (int j = 0; j < 4; j++) {
                float sv = acc[i][j][r];
                if (sv <= th) {
                    u32 code = (u32)(nTile + wn + j * 16 + (lane & 15));
                    u64 pk = ((u64)ford(sv) << 32) |
                             (u64)(((u32)(rowTile + lrow) << 13) | code);
                    u32 idx = atomicAdd(&ldsCnt, 1u);       // LDS atomic: cheap
                    if (idx < LCAP) candBuf[idx] = pk;
                    else { u32 g = atomicAdd(candCnt, 1u);  // rare overflow path
                           if (g < CAND_CAP) cand[g] = pk; }
                }
            }
        }
    }
    __syncthreads();
    if (tid == 0) {
        u32 n = ldsCnt < LCAP ? ldsCnt : LCAP;
        ldsBase = atomicAdd(candCnt, n);                    // ONE global atomic per block
    }
    __syncthreads();
    u32 n = ldsCnt < LCAP ? ldsCnt : LCAP;
    for (u32 k2 = tid; k2 < n; k2 += 256) {
        u32 g = ldsBase + k2;
        if (g < CAND_CAP) cand[g] = candBuf[k2];
    }
}

// ---------------- fp32 exact refine of pruned candidates ----------------
// R7-verified wave-parallel scan: 64 coalesced candidate loads/wave, parallel
// prune, ballot, full-wave 512-dot per survivor.
__global__ void k_refine(const float* __restrict__ z, const float* __restrict__ emb,
                         const float* __restrict__ en2, const u32* __restrict__ candCnt,
                         const u64* __restrict__ cand, const u32* __restrict__ rowMin,
                         u64* __restrict__ rowBest) {
    u32 cnt = *candCnt; if (cnt > CAND_CAP) cnt = CAND_CAP;
    int gt = blockIdx.x * blockDim.x + threadIdx.x;
    u32 wid = (u32)(gt >> 6);
    int lane = gt & 63;
    u32 nw = (u32)((gridDim.x * blockDim.x) >> 6);
    for (u32 base = wid * 64u; base < cnt; base += nw * 64u) {
        u32 ci = base + (u32)lane;
        u32 row = 0, code = 0;
        bool live = false;
        if (ci < cnt) {
            u64 pk = cand[ci];
            u32 rc = (u32)pk;
            row = rc >> 13; code = rc & (N_CODES - 1);
            float ad = fordinv((u32)(pk >> 32));
            float gm = fordinv(rowMin[row]);
            live = (ad <= gm + TAU2);
        }
        u64 mask = __ballot(live);
        while (mask) {
            int s = (int)(__ffsll((long long)mask) - 1);
            mask &= mask - 1;
            u32 srow  = __shfl(row,  s);
            u32 scode = __shfl(code, s);
            const float4* zp = (const float4*)(z + (size_t)srow * K_DIM) + lane * 2;
            const float4* ep = (const float4*)(emb + (size_t)scode * K_DIM) + lane * 2;
            float4 a0 = zp[0], a1 = zp[1], b0 = ep[0], b1 = ep[1];
            float d = a0.x*b0.x + a0.y*b0.y + a0.z*b0.z + a0.w*b0.w
                    + a1.x*b1.x + a1.y*b1.y + a1.z*b1.z + a1.w*b1.w;
            #pragma unroll
            for (int sh = 32; sh; sh >>= 1) d += __shfl_xor(d, sh);
            if (lane == 0) {
                float sv = en2[scode] - 2.0f * d;
                u64 bk = ((u64)ford(sv) << 32) | (u64)scode;
                atomicMin(rowBest + srow, bk);
            }
        }
    }
}

// -------- fused output + final: gather + codes + counts + loss, ticket -> scalars --------
// Regular launch (NO cooperative machinery — R8 showed that costs ~200us on this
// harness). 8192 blocks x 512 thr, 4 rows/block; loss partial = one LDS reduce +
// one float atomic per block; ticket's last block computes entropy + scalars
// (threadfence + atomic reads for cross-XCD visibility; pattern verified in R7).
__global__ void k_outfinal(const u64* __restrict__ rowBest, const float* __restrict__ emb,
                           const float* __restrict__ zn2, u32* __restrict__ counts,
                           float* __restrict__ out, float* __restrict__ fsum,
                           u32* __restrict__ ticket) {
    __shared__ float red4[4];
    __shared__ float red[256];
    __shared__ int lastBlk;
    int rl = threadIdx.x >> 7;          // 0..3 (row within block)
    int t  = threadIdx.x & 127;         // 128 thr/row, 4 floats each
    int row = blockIdx.x * 4 + rl;
    u64 pk = rowBest[row];
    u32 code = (u32)(pk & 0xFFFFFFFFull);
    float4 v = ((const float4*)(emb + (size_t)code * K_DIM))[t];
    ((float4*)(out + (size_t)row * K_DIM))[t] = v;
    if (t == 0) {
        out[OFF_CODES + row] = (float)code;
        atomicAdd(&counts[code], 1u);
        red4[rl] = zn2[row] + fordinv((u32)(pk >> 32));
    }
    __syncthreads();
    if (threadIdx.x == 0) {
        atomicAdd(fsum, red4[0] + red4[1] + red4[2] + red4[3]);
        __threadfence();
        lastBlk = (atomicAdd(ticket, 1u) == gridDim.x - 1) ? 1 : 0;
    }
    __syncthreads();
    if (!lastBlk) return;

    // last block: entropy over counts + final scalars
    int tt = threadIdx.x;
    float s2 = 0.f;
    for (int c = tt; c < N_CODES; c += 512) {
        float p = (float)atomicAdd(&counts[c], 0u) * (1.0f / (float)M_ROWS);
        s2 += p * logf(p + 1e-10f);
    }
    if (tt < 256) red[tt] = 0.f;
    __syncthreads();
    // fold 512 values into 256 slots then tree-reduce
    atomicAdd(&red[tt & 255], s2);   // LDS float atomics
    __syncthreads();
    for (int w = 128; w; w >>= 1) { if (tt < w) red[tt] += red[tt + w]; __syncthreads(); }
    if (tt == 0) {
        float lossSum = atomicAdd(fsum, 0.0f);
        out[OFF_LOSS] = 0.25f * lossSum / ((float)M_ROWS * (float)K_DIM);
        out[OFF_PERP] = expf(-red[0]);
    }
}

// ---------------- workspace layout (bytes) ----------------
#define WS_ZB      ((size_t)0)                       // 32768*512*2  = 33554432
#define WS_EB      ((size_t)33554432)                // 8192*512*2   = 8388608
#define WS_EN2     ((size_t)41943040)                // 8192*4
#define WS_ZN2     ((size_t)41975808)                // 32768*4
#define WS_ROWMIN  ((size_t)42106880)                // 32768*4
#define WS_ROWBEST ((size_t)42237952)                // 32768*8
#define WS_COUNTS  ((size_t)42500096)                // 8192*4
#define WS_CANDCNT ((size_t)42532864)                // candCnt @+0, fsum @+8, ticket @+12
#define WS_CAND    ((size_t)42533120)                // 3M*8 = 25165824 -> total ~67.7MB

extern "C" void kernel_launch(void* const* d_in, const int* in_sizes, int n_in,
                              void* d_out, int out_size, void* d_ws, size_t ws_size,
                              hipStream_t stream) {
    const float* z   = (const float*)d_in[0];
    const float* emb = (const float*)d_in[1];
    float* out = (float*)d_out;
    char* ws = (char*)d_ws;

    u16*  zb      = (u16*)(ws + WS_ZB);
    u16*  eb      = (u16*)(ws + WS_EB);
    float* en2    = (float*)(ws + WS_EN2);
    float* zn2    = (float*)(ws + WS_ZN2);
    u32*  rowMin  = (u32*)(ws + WS_ROWMIN);
    u64*  rowBest = (u64*)(ws + WS_ROWBEST);
    u32*  counts  = (u32*)(ws + WS_COUNTS);
    u32*  candCnt = (u32*)(ws + WS_CANDCNT);
    float* fsum   = (float*)(ws + WS_CANDCNT + 8);
    u32*  ticket  = (u32*)(ws + WS_CANDCNT + 12);
    u64*  cand    = (u64*)(ws + WS_CAND);

    // 1) fused convert (z + emb) + scratch init
    k_convert<<<dim3(8192 + 2048), dim3(256), 0, stream>>>(z, emb, zb, eb, zn2, en2,
                                                           rowMin, rowBest, counts, candCnt, fsum, ticket);
    // 2) GEMM + candidate capture (protected asset, unchanged)
    k_gemm<<<dim3(M_ROWS / BM, N_CODES / BN), dim3(256), 0, stream>>>(zb, eb, en2, rowMin, candCnt, cand);
    // 3) wave-parallel refine
    k_refine<<<dim3(1024), dim3(256), 0, stream>>>(z, emb, en2, candCnt, cand, rowMin, rowBest);
    // 4) fused output + final (ticket last-block pattern)
    k_outfinal<<<dim3(M_ROWS / 4), dim3(512), 0, stream>>>(rowBest, emb, zn2, counts, out, fsum, ticket);
}

// Round 10
// 626.966 us; speedup vs baseline: 1.3413x; 1.3413x over previous
//
#include <hip/hip_runtime.h>
#include <stdint.h>
#include <stddef.h>

// Problem constants (fixed by the reference)
#define M_ROWS 32768      // B*N = 16*2048
#define N_CODES 8192
#define K_DIM 512
#define BM 128
#define BN 128
#define BK 64
#define KITERS (K_DIM / BK)     // 8
#define CAND_CAP (3u*1024u*1024u)
#define LCAP 512u               // per-block LDS candidate slab
#define TAU2 2.0f               // 2*tau admission margin for bf16 approx distances (>10 sigma)

// Output layout (floats): z_q [0,16777216), codes [16777216,16809984), loss, perp
#define OFF_CODES 16777216
#define OFF_LOSS  (16777216 + 32768)
#define OFF_PERP  (16777216 + 32768 + 1)

using short8  = __attribute__((ext_vector_type(8))) short;
using ushort8 = __attribute__((ext_vector_type(8))) unsigned short;
using f32x4   = __attribute__((ext_vector_type(4))) float;

typedef unsigned short u16;
typedef unsigned int   u32;
typedef unsigned long long u64;

// ---- orderable-uint encoding of float (monotone: uint min == float min) ----
__device__ __forceinline__ u32 ford(float f) {
    u32 u = __float_as_uint(f);
    return (u & 0x80000000u) ? ~u : (u | 0x80000000u);
}
__device__ __forceinline__ float fordinv(u32 u) {
    u32 v = (u & 0x80000000u) ? (u & 0x7FFFFFFFu) : ~u;
    return __uint_as_float(v);
}
// fp32 -> bf16 (RNE)
__device__ __forceinline__ u16 f2bf(float f) {
    u32 u = __float_as_uint(f);
    u = u + 0x7FFFu + ((u >> 16) & 1u);
    return (u16)(u >> 16);
}

// async global->LDS, 16B per lane; LDS dest = wave-uniform base + lane*16
__device__ __forceinline__ void ldg_to_lds16(const u16* g, u16* l) {
    __builtin_amdgcn_global_load_lds((__attribute__((address_space(1))) void*)(g),
                                     (__attribute__((address_space(3))) void*)(l),
                                     16, 0, 0);
}

// ------------- fp32 -> bf16 convert + row squared norms (+ fused init) -------------
// The z-call (first launch) also performs all scratch init (saves the k_init launch):
// grid 8192x256 = 2.1M threads covers M_ROWS/N_CODES index ranges.
__global__ void k_convert(const float* __restrict__ src, u16* __restrict__ dst,
                          float* __restrict__ nrm2, int nrows,
                          u32* rowMin, u64* rowBest, u32* counts, u32* candCnt,
                          float* fsum, u32* ticket) {
    if (rowMin) {
        int g = blockIdx.x * blockDim.x + threadIdx.x;
        if (g < M_ROWS) { rowMin[g] = 0xFFFFFFFFu; rowBest[g] = ~0ull; }
        if (g < N_CODES) counts[g] = 0u;
        if (g == 0) { *candCnt = 0u; *fsum = 0.f; *ticket = 0u; }
    }
    int row  = blockIdx.x * 4 + (threadIdx.x >> 6);
    int lane = threadIdx.x & 63;
    if (row >= nrows) return;
    const float* p = src + (size_t)row * K_DIM + lane * 8;
    float4 a = *(const float4*)p;
    float4 b = *(const float4*)(p + 4);
    ushort8 v;
    v[0]=f2bf(a.x); v[1]=f2bf(a.y); v[2]=f2bf(a.z); v[3]=f2bf(a.w);
    v[4]=f2bf(b.x); v[5]=f2bf(b.y); v[6]=f2bf(b.z); v[7]=f2bf(b.w);
    *(ushort8*)(dst + (size_t)row * K_DIM + lane * 8) = v;
    float ss = a.x*a.x + a.y*a.y + a.z*a.z + a.w*a.w
             + b.x*b.x + b.y*b.y + b.z*b.z + b.w*b.w;
    #pragma unroll
    for (int s = 32; s; s >>= 1) ss += __shfl_xor(ss, s);
    if (lane == 0) nrm2[row] = ss;
}

// ---------------- main bf16 GEMM + fused min/candidate epilogue ----------------
// PROVEN baseline structure (R6/R7/R9: 420-423us, MfmaUtil 29%, Occ 41% = 4 blocks/CU).
// Coarse 2-barriers-per-K-step + 16 waves/CU cross-block overlap beats all
// fine-grained phase pipelines at this short K (R2-R5 evidence). DO NOT
// re-pipeline without first beating 420us in isolation. BYTE-IDENTICAL to R7.
__global__ __launch_bounds__(256, 4)
void k_gemm(const u16* __restrict__ zb, const u16* __restrict__ eb,
            const float* __restrict__ en2, u32* __restrict__ rowMin,
            u32* __restrict__ candCnt, u64* __restrict__ cand) {
    __shared__ __align__(16) u16 As[BM * BK];
    __shared__ __align__(16) u16 Bs[BN * BK];
    __shared__ float en2s[BN];
    __shared__ u32 threshL[BM];
    __shared__ u64 candBuf[LCAP];
    __shared__ u32 ldsCnt, ldsBase;

    const int tid  = threadIdx.x;
    const int lane = tid & 63;
    const int wave = tid >> 6;
    const int rowTile = blockIdx.x * BM;
    const int nTile   = blockIdx.y * BN;
    const int wm = (wave >> 1) * 64;   // wave's row quadrant
    const int wn = (wave & 1) * 64;    // wave's col quadrant

    if (tid < BN) { en2s[tid] = en2[nTile + tid]; threshL[tid] = 0xFFFFFFFFu; }
    if (tid == 0) ldsCnt = 0u;

    const int srow = (lane >> 3);
    const int sg   = (lane & 7) ^ ((lane >> 3) & 7);
    const u16* gA[4]; const u16* gB[4]; u16* lA[4]; u16* lB[4];
    #pragma unroll
    for (int t = 0; t < 4; t++) {
        int i = wave * 4 + t;
        gA[t] = zb + (size_t)(rowTile + i * 8 + srow) * K_DIM + sg * 8;
        gB[t] = eb + (size_t)(nTile   + i * 8 + srow) * K_DIM + sg * 8;
        lA[t] = As + i * 512;   // 64 blocks * 8 u16 per wave-issue
        lB[t] = Bs + i * 512;
    }

    int aoff[4], boff[4];
    const int q = lane >> 4;
    #pragma unroll
    for (int t = 0; t < 4; t++) {
        int R  = wm + t * 16 + (lane & 15);
        aoff[t] = (R * 8 + (q ^ (R & 7))) * 16;
        int Rn = wn + t * 16 + (lane & 15);
        boff[t] = (Rn * 8 + (q ^ (Rn & 7))) * 16;
    }

    f32x4 acc[4][4] = {};

    for (int kk = 0; kk < KITERS; kk++) {
        const int ko = kk * BK;
        #pragma unroll
        for (int t = 0; t < 4; t++) {
            ldg_to_lds16(gA[t] + ko, lA[t]);
            ldg_to_lds16(gB[t] + ko, lB[t]);
        }
        __syncthreads();
        short8 af[4], bf_[4];
        #pragma unroll
        for (int t = 0; t < 4; t++) {
            af[t]  = *(const short8*)((const char*)As + aoff[t]);
            bf_[t] = *(const short8*)((const char*)Bs + boff[t]);
        }
        #pragma unroll
        for (int i = 0; i < 4; i++)
            #pragma unroll
            for (int j = 0; j < 4; j++)
                acc[i][j] = __builtin_amdgcn_mfma_f32_16x16x32_bf16(af[i], bf_[j], acc[i][j], 0, 0, 0);
        #pragma unroll
        for (int t = 0; t < 4; t++) {
            af[t]  = *(const short8*)((const char*)As + (aoff[t] ^ 64));
            bf_[t] = *(const short8*)((const char*)Bs + (boff[t] ^ 64));
        }
        #pragma unroll
        for (int i = 0; i < 4; i++)
            #pragma unroll
            for (int j = 0; j < 4; j++)
                acc[i][j] = __builtin_amdgcn_mfma_f32_16x16x32_bf16(af[i], bf_[j], acc[i][j], 0, 0, 0);
        __syncthreads();
    }

    float e2v[4];
    #pragma unroll
    for (int j = 0; j < 4; j++) e2v[j] = en2s[wn + j * 16 + (lane & 15)];
    #pragma unroll
    for (int i = 0; i < 4; i++)
        #pragma unroll
        for (int j = 0; j < 4; j++)
            #pragma unroll
            for (int r = 0; r < 4; r++)
                acc[i][j][r] = e2v[j] - 2.0f * acc[i][j][r];

    float rm[4][4];
    #pragma unroll
    for (int i = 0; i < 4; i++)
        #pragma unroll
        for (int r = 0; r < 4; r++)
            rm[i][r] = fminf(fminf(acc[i][0][r], acc[i][1][r]),
                             fminf(acc[i][2][r], acc[i][3][r]));
    #pragma unroll
    for (int d = 1; d < 16; d <<= 1)
        #pragma unroll
        for (int i = 0; i < 4; i++)
            #pragma unroll
            for (int r = 0; r < 4; r++)
                rm[i][r] = fminf(rm[i][r], __shfl_xor(rm[i][r], d));

    if ((lane & 15) == 0) {
        #pragma unroll
        for (int i = 0; i < 4; i++)
            #pragma unroll
            for (int r = 0; r < 4; r++) {
                int lrow = wm + i * 16 + (lane >> 4) * 4 + r;
                u32 o = ford(rm[i][r]);
                atomicMin(&threshL[lrow], o);
                u32 old = atomicMin(&rowMin[rowTile + lrow], o);  // also tightens via earlier tiles
                atomicMin(&threshL[lrow], old);
            }
    }
    __syncthreads();

    #pragma unroll
    for (int i = 0; i < 4; i++) {
        #pragma unroll
        for (int r = 0; r < 4; r++) {
            int lrow = wm + i * 16 + (lane >> 4) * 4 + r;
            float th = fordinv(threshL[lrow]) + TAU2;
            #pragma unroll
            for (int j = 0; j < 4; j++) {
                float sv = acc[i][j][r];
                if (sv <= th) {
                    u32 code = (u32)(nTile + wn + j * 16 + (lane & 15));
                    u64 pk = ((u64)ford(sv) << 32) |
                             (u64)(((u32)(rowTile + lrow) << 13) | code);
                    u32 idx = atomicAdd(&ldsCnt, 1u);       // LDS atomic: cheap
                    if (idx < LCAP) candBuf[idx] = pk;
                    else { u32 g = atomicAdd(candCnt, 1u);  // rare overflow path
                           if (g < CAND_CAP) cand[g] = pk; }
                }
            }
        }
    }
    __syncthreads();
    if (tid == 0) {
        u32 n = ldsCnt < LCAP ? ldsCnt : LCAP;
        ldsBase = atomicAdd(candCnt, n);                    // ONE global atomic per block
    }
    __syncthreads();
    u32 n = ldsCnt < LCAP ? ldsCnt : LCAP;
    for (u32 k2 = tid; k2 < n; k2 += 256) {
        u32 g = ldsBase + k2;
        if (g < CAND_CAP) cand[g] = candBuf[k2];
    }
}

// ---------------- fp32 exact refine of pruned candidates ----------------
// R7-verified wave-parallel scan: 64 coalesced candidate loads/wave, parallel
// prune, ballot, full-wave 512-dot per survivor (~1% of candidates).
__global__ void k_refine(const float* __restrict__ z, const float* __restrict__ emb,
                         const float* __restrict__ en2, const u32* __restrict__ candCnt,
                         const u64* __restrict__ cand, const u32* __restrict__ rowMin,
                         u64* __restrict__ rowBest) {
    u32 cnt = *candCnt; if (cnt > CAND_CAP) cnt = CAND_CAP;
    int gt = blockIdx.x * blockDim.x + threadIdx.x;
    u32 wid = (u32)(gt >> 6);
    int lane = gt & 63;
    u32 nw = (u32)((gridDim.x * blockDim.x) >> 6);
    for (u32 base = wid * 64u; base < cnt; base += nw * 64u) {
        u32 ci = base + (u32)lane;
        u32 row = 0, code = 0;
        bool live = false;
        if (ci < cnt) {
            u64 pk = cand[ci];
            u32 rc = (u32)pk;
            row = rc >> 13; code = rc & (N_CODES - 1);
            float ad = fordinv((u32)(pk >> 32));
            float gm = fordinv(rowMin[row]);
            live = (ad <= gm + TAU2);
        }
        u64 mask = __ballot(live);
        while (mask) {
            int s = (int)(__ffsll((long long)mask) - 1);
            mask &= mask - 1;
            u32 srow  = __shfl(row,  s);
            u32 scode = __shfl(code, s);
            const float4* zp = (const float4*)(z + (size_t)srow * K_DIM) + lane * 2;
            const float4* ep = (const float4*)(emb + (size_t)scode * K_DIM) + lane * 2;
            float4 a0 = zp[0], a1 = zp[1], b0 = ep[0], b1 = ep[1];
            float d = a0.x*b0.x + a0.y*b0.y + a0.z*b0.z + a0.w*b0.w
                    + a1.x*b1.x + a1.y*b1.y + a1.z*b1.z + a1.w*b1.w;
            #pragma unroll
            for (int sh = 32; sh; sh >>= 1) d += __shfl_xor(d, sh);
            if (lane == 0) {
                float sv = en2[scode] - 2.0f * d;
                u64 bk = ((u64)ford(sv) << 32) | (u64)scode;
                atomicMin(rowBest + srow, bk);
            }
        }
    }
}

// ---------------- outputs: z_q gather, codes, counts ----------------
// R7-verified: 4 rows per block.
__global__ void k_output(const u64* __restrict__ rowBest, const float* __restrict__ emb,
                         float* __restrict__ out, u32* __restrict__ counts) {
    int row = blockIdx.x * 4 + (threadIdx.x >> 7);
    int t   = threadIdx.x & 127;   // 128 threads/row, 4 floats each
    u64 pk = rowBest[row];
    u32 code = (u32)(pk & 0xFFFFFFFFull);
    float4 v = ((const float4*)(emb + (size_t)code * K_DIM))[t];
    ((float4*)(out + (size_t)row * K_DIM))[t] = v;
    if (t == 0) {
        out[OFF_CODES + row] = (float)code;
        atomicAdd(&counts[code], 1u);
    }
}

// ---------------- loss + perplexity ----------------
// R7-verified: 32-block partial sums + ticket; last block reads the device-scope
// sum via atomicAdd(fsum, 0) and computes the 8192-entry entropy + final scalars.
__global__ void k_final(const u64* __restrict__ rowBest, const float* __restrict__ zn2,
                        const u32* __restrict__ counts, float* __restrict__ out,
                        float* __restrict__ fsum, u32* __restrict__ ticket) {
    __shared__ float red[256];
    __shared__ int lastBlk;
    __shared__ float lossSumSh;
    int t = threadIdx.x;
    float s1 = 0.f;
    for (int r = blockIdx.x * 256 + t; r < M_ROWS; r += gridDim.x * 256)
        s1 += zn2[r] + fordinv((u32)(rowBest[r] >> 32));
    red[t] = s1; __syncthreads();
    for (int w = 128; w; w >>= 1) { if (t < w) red[t] += red[t + w]; __syncthreads(); }
    if (t == 0) {
        atomicAdd(fsum, red[0]);
        __threadfence();
        lastBlk = (atomicAdd(ticket, 1u) == gridDim.x - 1) ? 1 : 0;
    }
    __syncthreads();
    if (!lastBlk) return;
    if (t == 0) lossSumSh = atomicAdd(fsum, 0.0f);   // device-scope read of total
    float s2 = 0.f;
    for (int c = t; c < N_CODES; c += 256) {
        float p = (float)counts[c] * (1.0f / (float)M_ROWS);
        s2 += p * logf(p + 1e-10f);
    }
    red[t] = s2; __syncthreads();
    for (int w = 128; w; w >>= 1) { if (t < w) red[t] += red[t + w]; __syncthreads(); }
    if (t == 0) {
        out[OFF_LOSS] = 0.25f * lossSumSh / ((float)M_ROWS * (float)K_DIM);
        out[OFF_PERP] = expf(-red[0]);
    }
}

// ---------------- workspace layout (bytes) ----------------
#define WS_ZB      ((size_t)0)                       // 32768*512*2  = 33554432
#define WS_EB      ((size_t)33554432)                // 8192*512*2   = 8388608
#define WS_EN2     ((size_t)41943040)                // 8192*4
#define WS_ZN2     ((size_t)41975808)                // 32768*4
#define WS_ROWMIN  ((size_t)42106880)                // 32768*4
#define WS_ROWBEST ((size_t)42237952)                // 32768*8
#define WS_COUNTS  ((size_t)42500096)                // 8192*4
#define WS_CANDCNT ((size_t)42532864)                // candCnt @+0, fsum @+8, ticket @+12
#define WS_CAND    ((size_t)42533120)                // 3M*8 = 25165824 -> total ~67.7MB

extern "C" void kernel_launch(void* const* d_in, const int* in_sizes, int n_in,
                              void* d_out, int out_size, void* d_ws, size_t ws_size,
                              hipStream_t stream) {
    const float* z   = (const float*)d_in[0];
    const float* emb = (const float*)d_in[1];
    float* out = (float*)d_out;
    char* ws = (char*)d_ws;

    u16*  zb      = (u16*)(ws + WS_ZB);
    u16*  eb      = (u16*)(ws + WS_EB);
    float* en2    = (float*)(ws + WS_EN2);
    float* zn2    = (float*)(ws + WS_ZN2);
    u32*  rowMin  = (u32*)(ws + WS_ROWMIN);
    u64*  rowBest = (u64*)(ws + WS_ROWBEST);
    u32*  counts  = (u32*)(ws + WS_COUNTS);
    u32*  candCnt = (u32*)(ws + WS_CANDCNT);
    float* fsum   = (float*)(ws + WS_CANDCNT + 8);
    u32*  ticket  = (u32*)(ws + WS_CANDCNT + 12);
    u64*  cand    = (u64*)(ws + WS_CAND);

    // z-convert also performs all scratch init (grid covers all init ranges)
    k_convert<<<dim3(M_ROWS / 4), dim3(256), 0, stream>>>(z, zb, zn2, M_ROWS,
                                                          rowMin, rowBest, counts, candCnt, fsum, ticket);
    k_convert<<<dim3(N_CODES / 4), dim3(256), 0, stream>>>(emb, eb, en2, N_CODES,
                                                           nullptr, nullptr, nullptr, nullptr, nullptr, nullptr);
    k_gemm<<<dim3(M_ROWS / BM, N_CODES / BN), dim3(256), 0, stream>>>(zb, eb, en2, rowMin, candCnt, cand);
    k_refine<<<dim3(1024), dim3(256), 0, stream>>>(z, emb, en2, candCnt, cand, rowMin, rowBest);
    k_output<<<dim3(M_ROWS / 4), dim3(512), 0, stream>>>(rowBest, emb, out, counts);
    k_final<<<dim3(32), dim3(256), 0, stream>>>(rowBest, zn2, counts, out, fsum, ticket);
}

// Round 11
// 584.941 us; speedup vs baseline: 1.4377x; 1.0718x over previous
//
#include <hip/hip_runtime.h>
#include <stdint.h>
#include <stddef.h>

// Problem constants (fixed by the reference)
#define M_ROWS 32768      // B*N = 16*2048
#define N_CODES 8192
#define K_DIM 512
#define BM 128
#define BN 128
#define BK 64
#define KITERS (K_DIM / BK)     // 8
#define CAND_CAP (3u*1024u*1024u)
#define LCAP 768u               // R11: 512->768. LDS total 39944B x4 = 159.8KB <= 160KB,
                                // still 4 blocks/CU. Probes the slab-overflow global-atomic
                                // path (WRITE_SIZE shows ~516 cands/block vs old cap 512).
#define TAU2 2.0f               // 2*tau admission margin for bf16 approx distances (>10 sigma)

// Output layout (floats): z_q [0,16777216), codes [16777216,16809984), loss, perp
#define OFF_CODES 16777216
#define OFF_LOSS  (16777216 + 32768)
#define OFF_PERP  (16777216 + 32768 + 1)

using short8  = __attribute__((ext_vector_type(8))) short;
using ushort8 = __attribute__((ext_vector_type(8))) unsigned short;
using f32x4   = __attribute__((ext_vector_type(4))) float;

typedef unsigned short u16;
typedef unsigned int   u32;
typedef unsigned long long u64;

// ---- orderable-uint encoding of float (monotone: uint min == float min) ----
__device__ __forceinline__ u32 ford(float f) {
    u32 u = __float_as_uint(f);
    return (u & 0x80000000u) ? ~u : (u | 0x80000000u);
}
__device__ __forceinline__ float fordinv(u32 u) {
    u32 v = (u & 0x80000000u) ? (u & 0x7FFFFFFFu) : ~u;
    return __uint_as_float(v);
}
// fp32 -> bf16 (RNE)
__device__ __forceinline__ u16 f2bf(float f) {
    u32 u = __float_as_uint(f);
    u = u + 0x7FFFu + ((u >> 16) & 1u);
    return (u16)(u >> 16);
}

// async global->LDS, 16B per lane; LDS dest = wave-uniform base + lane*16
__device__ __forceinline__ void ldg_to_lds16(const u16* g, u16* l) {
    __builtin_amdgcn_global_load_lds((__attribute__((address_space(1))) void*)(g),
                                     (__attribute__((address_space(3))) void*)(l),
                                     16, 0, 0);
}

// ------------- fp32 -> bf16 convert + row squared norms (+ fused init) -------------
// The z-call (first launch) also performs all scratch init (saves the k_init launch):
// grid 8192x256 = 2.1M threads covers M_ROWS/N_CODES index ranges.
__global__ void k_convert(const float* __restrict__ src, u16* __restrict__ dst,
                          float* __restrict__ nrm2, int nrows,
                          u32* rowMin, u64* rowBest, u32* counts, u32* candCnt,
                          float* fsum, u32* ticket) {
    if (rowMin) {
        int g = blockIdx.x * blockDim.x + threadIdx.x;
        if (g < M_ROWS) { rowMin[g] = 0xFFFFFFFFu; rowBest[g] = ~0ull; }
        if (g < N_CODES) counts[g] = 0u;
        if (g == 0) { *candCnt = 0u; *fsum = 0.f; *ticket = 0u; }
    }
    int row  = blockIdx.x * 4 + (threadIdx.x >> 6);
    int lane = threadIdx.x & 63;
    if (row >= nrows) return;
    const float* p = src + (size_t)row * K_DIM + lane * 8;
    float4 a = *(const float4*)p;
    float4 b = *(const float4*)(p + 4);
    ushort8 v;
    v[0]=f2bf(a.x); v[1]=f2bf(a.y); v[2]=f2bf(a.z); v[3]=f2bf(a.w);
    v[4]=f2bf(b.x); v[5]=f2bf(b.y); v[6]=f2bf(b.z); v[7]=f2bf(b.w);
    *(ushort8*)(dst + (size_t)row * K_DIM + lane * 8) = v;
    float ss = a.x*a.x + a.y*a.y + a.z*a.z + a.w*a.w
             + b.x*b.x + b.y*b.y + b.z*b.z + b.w*b.w;
    #pragma unroll
    for (int s = 32; s; s >>= 1) ss += __shfl_xor(ss, s);
    if (lane == 0) nrm2[row] = ss;
}

// ---------------- main bf16 GEMM + fused min/candidate epilogue ----------------
// PROVEN baseline structure (R6/R7/R10: 419-423us, MfmaUtil 29%, Occ 42% = 4 blocks/CU).
// Coarse 2-barriers-per-K-step + 16 waves/CU cross-block overlap beats all
// fine-grained phase pipelines at this short K (R2-R5 evidence). DO NOT
// re-pipeline without first beating 419us in isolation.
// R11 single change: LCAP 512->768 (see above). Everything else byte-identical.
__global__ __launch_bounds__(256, 4)
void k_gemm(const u16* __restrict__ zb, const u16* __restrict__ eb,
            const float* __restrict__ en2, u32* __restrict__ rowMin,
            u32* __restrict__ candCnt, u64* __restrict__ cand) {
    __shared__ __align__(16) u16 As[BM * BK];
    __shared__ __align__(16) u16 Bs[BN * BK];
    __shared__ float en2s[BN];
    __shared__ u32 threshL[BM];
    __shared__ u64 candBuf[LCAP];
    __shared__ u32 ldsCnt, ldsBase;

    const int tid  = threadIdx.x;
    const int lane = tid & 63;
    const int wave = tid >> 6;
    const int rowTile = blockIdx.x * BM;
    const int nTile   = blockIdx.y * BN;
    const int wm = (wave >> 1) * 64;   // wave's row quadrant
    const int wn = (wave & 1) * 64;    // wave's col quadrant

    if (tid < BN) { en2s[tid] = en2[nTile + tid]; threshL[tid] = 0xFFFFFFFFu; }
    if (tid == 0) ldsCnt = 0u;

    const int srow = (lane >> 3);
    const int sg   = (lane & 7) ^ ((lane >> 3) & 7);
    const u16* gA[4]; const u16* gB[4]; u16* lA[4]; u16* lB[4];
    #pragma unroll
    for (int t = 0; t < 4; t++) {
        int i = wave * 4 + t;
        gA[t] = zb + (size_t)(rowTile + i * 8 + srow) * K_DIM + sg * 8;
        gB[t] = eb + (size_t)(nTile   + i * 8 + srow) * K_DIM + sg * 8;
        lA[t] = As + i * 512;   // 64 blocks * 8 u16 per wave-issue
        lB[t] = Bs + i * 512;
    }

    int aoff[4], boff[4];
    const int q = lane >> 4;
    #pragma unroll
    for (int t = 0; t < 4; t++) {
        int R  = wm + t * 16 + (lane & 15);
        aoff[t] = (R * 8 + (q ^ (R & 7))) * 16;
        int Rn = wn + t * 16 + (lane & 15);
        boff[t] = (Rn * 8 + (q ^ (Rn & 7))) * 16;
    }

    f32x4 acc[4][4] = {};

    for (int kk = 0; kk < KITERS; kk++) {
        const int ko = kk * BK;
        #pragma unroll
        for (int t = 0; t < 4; t++) {
            ldg_to_lds16(gA[t] + ko, lA[t]);
            ldg_to_lds16(gB[t] + ko, lB[t]);
        }
        __syncthreads();
        short8 af[4], bf_[4];
        #pragma unroll
        for (int t = 0; t < 4; t++) {
            af[t]  = *(const short8*)((const char*)As + aoff[t]);
            bf_[t] = *(const short8*)((const char*)Bs + boff[t]);
        }
        #pragma unroll
        for (int i = 0; i < 4; i++)
            #pragma unroll
            for (int j = 0; j < 4; j++)
                acc[i][j] = __builtin_amdgcn_mfma_f32_16x16x32_bf16(af[i], bf_[j], acc[i][j], 0, 0, 0);
        #pragma unroll
        for (int t = 0; t < 4; t++) {
            af[t]  = *(const short8*)((const char*)As + (aoff[t] ^ 64));
            bf_[t] = *(const short8*)((const char*)Bs + (boff[t] ^ 64));
        }
        #pragma unroll
        for (int i = 0; i < 4; i++)
            #pragma unroll
            for (int j = 0; j < 4; j++)
                acc[i][j] = __builtin_amdgcn_mfma_f32_16x16x32_bf16(af[i], bf_[j], acc[i][j], 0, 0, 0);
        __syncthreads();
    }

    float e2v[4];
    #pragma unroll
    for (int j = 0; j < 4; j++) e2v[j] = en2s[wn + j * 16 + (lane & 15)];
    #pragma unroll
    for (int i = 0; i < 4; i++)
        #pragma unroll
        for (int j = 0; j < 4; j++)
            #pragma unroll
            for (int r = 0; r < 4; r++)
                acc[i][j][r] = e2v[j] - 2.0f * acc[i][j][r];

    float rm[4][4];
    #pragma unroll
    for (int i = 0; i < 4; i++)
        #pragma unroll
        for (int r = 0; r < 4; r++)
            rm[i][r] = fminf(fminf(acc[i][0][r], acc[i][1][r]),
                             fminf(acc[i][2][r], acc[i][3][r]));
    #pragma unroll
    for (int d = 1; d < 16; d <<= 1)
        #pragma unroll
        for (int i = 0; i < 4; i++)
            #pragma unroll
            for (int r = 0; r < 4; r++)
                rm[i][r] = fminf(rm[i][r], __shfl_xor(rm[i][r], d));

    if ((lane & 15) == 0) {
        #pragma unroll
        for (int i = 0; i < 4; i++)
            #pragma unroll
            for (int r = 0; r < 4; r++) {
                int lrow = wm + i * 16 + (lane >> 4) * 4 + r;
                u32 o = ford(rm[i][r]);
                atomicMin(&threshL[lrow], o);
                u32 old = atomicMin(&rowMin[rowTile + lrow], o);  // also tightens via earlier tiles
                atomicMin(&threshL[lrow], old);
            }
    }
    __syncthreads();

    #pragma unroll
    for (int i = 0; i < 4; i++) {
        #pragma unroll
        for (int r = 0; r < 4; r++) {
            int lrow = wm + i * 16 + (lane >> 4) * 4 + r;
            float th = fordinv(threshL[lrow]) + TAU2;
            #pragma unroll
            for (int j = 0; j < 4; j++) {
                float sv = acc[i][j][r];
                if (sv <= th) {
                    u32 code = (u32)(nTile + wn + j * 16 + (lane & 15));
                    u64 pk = ((u64)ford(sv) << 32) |
                             (u64)(((u32)(rowTile + lrow) << 13) | code);
                    u32 idx = atomicAdd(&ldsCnt, 1u);       // LDS atomic: cheap
                    if (idx < LCAP) candBuf[idx] = pk;
                    else { u32 g = atomicAdd(candCnt, 1u);  // rare overflow path
                           if (g < CAND_CAP) cand[g] = pk; }
                }
            }
        }
    }
    __syncthreads();
    if (tid == 0) {
        u32 n = ldsCnt < LCAP ? ldsCnt : LCAP;
        ldsBase = atomicAdd(candCnt, n);                    // ONE global atomic per block
    }
    __syncthreads();
    u32 n = ldsCnt < LCAP ? ldsCnt : LCAP;
    for (u32 k2 = tid; k2 < n; k2 += 256) {
        u32 g = ldsBase + k2;
        if (g < CAND_CAP) cand[g] = candBuf[k2];
    }
}

// ---------------- fp32 exact refine of pruned candidates ----------------
// R7-verified wave-parallel scan: 64 coalesced candidate loads/wave, parallel
// prune, ballot, full-wave 512-dot per survivor (~1% of candidates).
__global__ void k_refine(const float* __restrict__ z, const float* __restrict__ emb,
                         const float* __restrict__ en2, const u32* __restrict__ candCnt,
                         const u64* __restrict__ cand, const u32* __restrict__ rowMin,
                         u64* __restrict__ rowBest) {
    u32 cnt = *candCnt; if (cnt > CAND_CAP) cnt = CAND_CAP;
    int gt = blockIdx.x * blockDim.x + threadIdx.x;
    u32 wid = (u32)(gt >> 6);
    int lane = gt & 63;
    u32 nw = (u32)((gridDim.x * blockDim.x) >> 6);
    for (u32 base = wid * 64u; base < cnt; base += nw * 64u) {
        u32 ci = base + (u32)lane;
        u32 row = 0, code = 0;
        bool live = false;
        if (ci < cnt) {
            u64 pk = cand[ci];
            u32 rc = (u32)pk;
            row = rc >> 13; code = rc & (N_CODES - 1);
            float ad = fordinv((u32)(pk >> 32));
            float gm = fordinv(rowMin[row]);
            live = (ad <= gm + TAU2);
        }
        u64 mask = __ballot(live);
        while (mask) {
            int s = (int)(__ffsll((long long)mask) - 1);
            mask &= mask - 1;
            u32 srow  = __shfl(row,  s);
            u32 scode = __shfl(code, s);
            const float4* zp = (const float4*)(z + (size_t)srow * K_DIM) + lane * 2;
            const float4* ep = (const float4*)(emb + (size_t)scode * K_DIM) + lane * 2;
            float4 a0 = zp[0], a1 = zp[1], b0 = ep[0], b1 = ep[1];
            float d = a0.x*b0.x + a0.y*b0.y + a0.z*b0.z + a0.w*b0.w
                    + a1.x*b1.x + a1.y*b1.y + a1.z*b1.z + a1.w*b1.w;
            #pragma unroll
            for (int sh = 32; sh; sh >>= 1) d += __shfl_xor(d, sh);
            if (lane == 0) {
                float sv = en2[scode] - 2.0f * d;
                u64 bk = ((u64)ford(sv) << 32) | (u64)scode;
                atomicMin(rowBest + srow, bk);
            }
        }
    }
}

// ---------------- outputs: z_q gather, codes, counts ----------------
// R7-verified: 4 rows per block.
__global__ void k_output(const u64* __restrict__ rowBest, const float* __restrict__ emb,
                         float* __restrict__ out, u32* __restrict__ counts) {
    int row = blockIdx.x * 4 + (threadIdx.x >> 7);
    int t   = threadIdx.x & 127;   // 128 threads/row, 4 floats each
    u64 pk = rowBest[row];
    u32 code = (u32)(pk & 0xFFFFFFFFull);
    float4 v = ((const float4*)(emb + (size_t)code * K_DIM))[t];
    ((float4*)(out + (size_t)row * K_DIM))[t] = v;
    if (t == 0) {
        out[OFF_CODES + row] = (float)code;
        atomicAdd(&counts[code], 1u);
    }
}

// ---------------- loss + perplexity ----------------
// R7-verified: 32-block partial sums + ticket; last block reads the device-scope
// sum via atomicAdd(fsum, 0) and computes the 8192-entry entropy + final scalars.
__global__ void k_final(const u64* __restrict__ rowBest, const float* __restrict__ zn2,
                        const u32* __restrict__ counts, float* __restrict__ out,
                        float* __restrict__ fsum, u32* __restrict__ ticket) {
    __shared__ float red[256];
    __shared__ int lastBlk;
    __shared__ float lossSumSh;
    int t = threadIdx.x;
    float s1 = 0.f;
    for (int r = blockIdx.x * 256 + t; r < M_ROWS; r += gridDim.x * 256)
        s1 += zn2[r] + fordinv((u32)(rowBest[r] >> 32));
    red[t] = s1; __syncthreads();
    for (int w = 128; w; w >>= 1) { if (t < w) red[t] += red[t + w]; __syncthreads(); }
    if (t == 0) {
        atomicAdd(fsum, red[0]);
        __threadfence();
        lastBlk = (atomicAdd(ticket, 1u) == gridDim.x - 1) ? 1 : 0;
    }
    __syncthreads();
    if (!lastBlk) return;
    if (t == 0) lossSumSh = atomicAdd(fsum, 0.0f);   // device-scope read of total
    float s2 = 0.f;
    for (int c = t; c < N_CODES; c += 256) {
        float p = (float)counts[c] * (1.0f / (float)M_ROWS);
        s2 += p * logf(p + 1e-10f);
    }
    red[t] = s2; __syncthreads();
    for (int w = 128; w; w >>= 1) { if (t < w) red[t] += red[t + w]; __syncthreads(); }
    if (t == 0) {
        out[OFF_LOSS] = 0.25f * lossSumSh / ((float)M_ROWS * (float)K_DIM);
        out[OFF_PERP] = expf(-red[0]);
    }
}

// ---------------- workspace layout (bytes) ----------------
#define WS_ZB      ((size_t)0)                       // 32768*512*2  = 33554432
#define WS_EB      ((size_t)33554432)                // 8192*512*2   = 8388608
#define WS_EN2     ((size_t)41943040)                // 8192*4
#define WS_ZN2     ((size_t)41975808)                // 32768*4
#define WS_ROWMIN  ((size_t)42106880)                // 32768*4
#define WS_ROWBEST ((size_t)42237952)                // 32768*8
#define WS_COUNTS  ((size_t)42500096)                // 8192*4
#define WS_CANDCNT ((size_t)42532864)                // candCnt @+0, fsum @+8, ticket @+12
#define WS_CAND    ((size_t)42533120)                // 3M*8 = 25165824 -> total ~67.7MB

extern "C" void kernel_launch(void* const* d_in, const int* in_sizes, int n_in,
                              void* d_out, int out_size, void* d_ws, size_t ws_size,
                              hipStream_t stream) {
    const float* z   = (const float*)d_in[0];
    const float* emb = (const float*)d_in[1];
    float* out = (float*)d_out;
    char* ws = (char*)d_ws;

    u16*  zb      = (u16*)(ws + WS_ZB);
    u16*  eb      = (u16*)(ws + WS_EB);
    float* en2    = (float*)(ws + WS_EN2);
    float* zn2    = (float*)(ws + WS_ZN2);
    u32*  rowMin  = (u32*)(ws + WS_ROWMIN);
    u64*  rowBest = (u64*)(ws + WS_ROWBEST);
    u32*  counts  = (u32*)(ws + WS_COUNTS);
    u32*  candCnt = (u32*)(ws + WS_CANDCNT);
    float* fsum   = (float*)(ws + WS_CANDCNT + 8);
    u32*  ticket  = (u32*)(ws + WS_CANDCNT + 12);
    u64*  cand    = (u64*)(ws + WS_CAND);

    // z-convert also performs all scratch init (grid covers all init ranges)
    k_convert<<<dim3(M_ROWS / 4), dim3(256), 0, stream>>>(z, zb, zn2, M_ROWS,
                                                          rowMin, rowBest, counts, candCnt, fsum, ticket);
    k_convert<<<dim3(N_CODES / 4), dim3(256), 0, stream>>>(emb, eb, en2, N_CODES,
                                                           nullptr, nullptr, nullptr, nullptr, nullptr, nullptr);
    k_gemm<<<dim3(M_ROWS / BM, N_CODES / BN), dim3(256), 0, stream>>>(zb, eb, en2, rowMin, candCnt, cand);
    k_refine<<<dim3(1024), dim3(256), 0, stream>>>(z, emb, en2, candCnt, cand, rowMin, rowBest);
    k_output<<<dim3(M_ROWS / 4), dim3(512), 0, stream>>>(rowBest, emb, out, counts);
    k_final<<<dim3(32), dim3(256), 0, stream>>>(rowBest, zn2, counts, out, fsum, ticket);
}